// Round 1
// baseline (1180.066 us; speedup 1.0000x reference)
//
#include <hip/hip_runtime.h>
#include <hip/hip_bf16.h>

// Problem: out = softmax(h @ fc_w^T + fc_b), h from embedding+LSTM step.
// VOCAB=100000, EMBED=100, NOISE=10, HIDDEN=128, BATCH=2048.
// f-gate dead (c0=0), W_hh dead (h0=0).
// Strategy:
//   k1: lstm_h  -> h[2048][128] in bf16 (ws), zero rowsum (ws)
//   k2: GEMM pass1 (MFMA bf16): rowsum[b] = sum_v exp(logit[b][v])  (no big write)
//   k3: rowsum -> 1/rowsum
//   k4: GEMM pass2: out[b][v] = exp(logit[b][v]) * inv[b]   (819 MB write, HBM-bound)

typedef __bf16 bf16x8 __attribute__((ext_vector_type(8)));
typedef float  f32x4  __attribute__((ext_vector_type(4)));

#define VOCAB    100000
#define EMBED    100
#define NOISE_D  10
#define HIDDEN   128
#define BATCH    2048
#define NSPLIT   125                      // N blocks along vocab
#define COLS_PER_BLOCK (VOCAB / NSPLIT)   // 800, exact
#define NCHUNKS  (COLS_PER_BLOCK / 16)    // 50 chunks of 16 cols

__global__ __launch_bounds__(128) void lstm_h_kernel(
    const int* __restrict__ idx, const float* __restrict__ noise,
    const float* __restrict__ emb, const float* __restrict__ W_ih,
    const float* __restrict__ b_ih, const float* __restrict__ b_hh,
    __bf16* __restrict__ h_out, float* __restrict__ rowsum)
{
    __shared__ float xs[EMBED + NOISE_D];
    const int b = blockIdx.x, t = threadIdx.x;
    if (t < EMBED)                xs[t] = emb[(long)idx[b] * EMBED + t];
    else if (t < EMBED + NOISE_D) xs[t] = noise[b * NOISE_D + (t - EMBED)];
    if (t == 0) rowsum[b] = 0.0f;   // ws is poisoned 0xAA: must init every call
    __syncthreads();

    // gate rows: i = t, (f = 128+t dead), g = 256+t, o = 384+t
    float gi = b_ih[t]       + b_hh[t];
    float gg = b_ih[256 + t] + b_hh[256 + t];
    float go = b_ih[384 + t] + b_hh[384 + t];
    const float* wi = W_ih + (long)t * 110;
    const float* wg = W_ih + (long)(256 + t) * 110;
    const float* wo = W_ih + (long)(384 + t) * 110;
    // 110 = 55 float2 (rows are 8-byte aligned: 440*t bytes)
    #pragma unroll 5
    for (int k = 0; k < 55; ++k) {
        float2 a = *(const float2*)(wi + 2 * k);
        float2 g2 = *(const float2*)(wg + 2 * k);
        float2 o2 = *(const float2*)(wo + 2 * k);
        float x0 = xs[2 * k], x1 = xs[2 * k + 1];
        gi = fmaf(a.x, x0, gi);  gi = fmaf(a.y, x1, gi);
        gg = fmaf(g2.x, x0, gg); gg = fmaf(g2.y, x1, gg);
        go = fmaf(o2.x, x0, go); go = fmaf(o2.y, x1, go);
    }
    float si = 1.0f / (1.0f + __expf(-gi));
    float c  = si * tanhf(gg);               // c0 == 0 so f-gate contributes 0
    float so = 1.0f / (1.0f + __expf(-go));
    float h  = so * tanhf(c);
    h_out[b * HIDDEN + t] = (__bf16)h;
}

__global__ void inv_kernel(float* __restrict__ rowsum)
{
    int i = blockIdx.x * 256 + threadIdx.x;
    if (i < BATCH) rowsum[i] = 1.0f / rowsum[i];
}

// Each wave owns 64 rows; full K=128 of A held in registers (16 bf16x8 = 64 VGPRs).
// B (fc_w) streams via LDS in 16-col chunks, fp32->bf16 converted at stage time.
// MFMA 16x16x32 layouts (HW-verified m89/m120):
//   A: m = lane&15, k = (lane>>4)*8 + j
//   B: n = lane&15, k = (lane>>4)*8 + j   (k-contiguous == fc_w row-major)
//   D: col = lane&15, row = (lane>>4)*4 + reg
template<bool PASS2>
__global__ __launch_bounds__(256) void gemm_softmax_kernel(
    const __bf16* __restrict__ hb, const float* __restrict__ fc_w,
    const float* __restrict__ fc_b, float* __restrict__ rowsum,
    float* __restrict__ out)
{
    __shared__ __bf16 Bs[16][136];   // +8 bf16 pad: 4-bank row shift, 16B-aligned rows

    const int tid  = threadIdx.x;
    const int wave = tid >> 6, lane = tid & 63;
    const int quad = lane >> 4, l16 = lane & 15;
    const int mbase = blockIdx.y * 256 + wave * 64;   // this wave's 64 rows
    const int nbase = blockIdx.x * COLS_PER_BLOCK;

    // A fragments: 4 m-subtiles x 4 k-steps, resident for the whole kernel
    bf16x8 a[4][4];
    #pragma unroll
    for (int ms = 0; ms < 4; ++ms) {
        const __bf16* arow = hb + (long)(mbase + ms * 16 + l16) * HIDDEN + quad * 8;
        #pragma unroll
        for (int ks = 0; ks < 4; ++ks)
            a[ms][ks] = *(const bf16x8*)(arow + ks * 32);
    }

    float sums[4][4];
    float inv[4][4];
    #pragma unroll
    for (int ms = 0; ms < 4; ++ms)
        #pragma unroll
        for (int r = 0; r < 4; ++r) {
            if (PASS2) inv[ms][r] = rowsum[mbase + ms * 16 + quad * 4 + r];
            else       sums[ms][r] = 0.0f;
        }

    for (int ch = 0; ch < NCHUNKS; ++ch) {
        const int n0 = nbase + ch * 16;
        // stage B chunk: 16 rows x 128 k fp32 -> bf16 LDS (2048 floats, 8/thread)
        {
            const int fi = tid * 8;
            const int r = fi >> 7, k = fi & 127;
            const float* src = fc_w + (long)(n0 + r) * HIDDEN + k;
            f32x4 v0 = *(const f32x4*)(src);
            f32x4 v1 = *(const f32x4*)(src + 4);
            bf16x8 w;
            w[0] = (__bf16)v0[0]; w[1] = (__bf16)v0[1];
            w[2] = (__bf16)v0[2]; w[3] = (__bf16)v0[3];
            w[4] = (__bf16)v1[0]; w[5] = (__bf16)v1[1];
            w[6] = (__bf16)v1[2]; w[7] = (__bf16)v1[3];
            *(bf16x8*)(&Bs[r][k]) = w;
        }
        __syncthreads();

        f32x4 acc[4];
        #pragma unroll
        for (int ms = 0; ms < 4; ++ms)
            #pragma unroll
            for (int e = 0; e < 4; ++e) acc[ms][e] = 0.0f;

        #pragma unroll
        for (int ks = 0; ks < 4; ++ks) {
            bf16x8 bfrag = *(const bf16x8*)(&Bs[l16][ks * 32 + quad * 8]);
            #pragma unroll
            for (int ms = 0; ms < 4; ++ms)
                acc[ms] = __builtin_amdgcn_mfma_f32_16x16x32_bf16(
                    a[ms][ks], bfrag, acc[ms], 0, 0, 0);
        }

        const float bias = fc_b[n0 + l16];
        #pragma unroll
        for (int ms = 0; ms < 4; ++ms)
            #pragma unroll
            for (int r = 0; r < 4; ++r) {
                float e = __expf(acc[ms][r] + bias);
                if (PASS2) {
                    const int row = mbase + ms * 16 + quad * 4 + r;
                    out[(long)row * VOCAB + n0 + l16] = e * inv[ms][r];
                } else {
                    sums[ms][r] += e;
                }
            }
        __syncthreads();   // Bs reused next chunk
    }

    if (!PASS2) {
        // reduce each row's partial across the 16 lanes of its column group
        #pragma unroll
        for (int ms = 0; ms < 4; ++ms)
            #pragma unroll
            for (int r = 0; r < 4; ++r) {
                float s = sums[ms][r];
                s += __shfl_xor(s, 1);
                s += __shfl_xor(s, 2);
                s += __shfl_xor(s, 4);
                s += __shfl_xor(s, 8);
                if (l16 == 0)
                    atomicAdd(&rowsum[mbase + ms * 16 + quad * 4 + r], s);
            }
    }
}

extern "C" void kernel_launch(void* const* d_in, const int* in_sizes, int n_in,
                              void* d_out, int out_size, void* d_ws, size_t ws_size,
                              hipStream_t stream)
{
    const int*   xi    = (const int*)  d_in[0];
    const float* noise = (const float*)d_in[1];
    const float* emb   = (const float*)d_in[2];
    const float* W_ih  = (const float*)d_in[3];
    // d_in[4] = W_hh: dead (h0 == 0)
    const float* b_ih  = (const float*)d_in[5];
    const float* b_hh  = (const float*)d_in[6];
    const float* fc_w  = (const float*)d_in[7];
    const float* fc_b  = (const float*)d_in[8];
    float* out = (float*)d_out;

    // ws layout: [0,8KB) rowsum fp32[2048]; [8KB, 8KB+512KB) h bf16[2048*128]
    float*  rowsum = (float*)d_ws;
    __bf16* hb     = (__bf16*)((char*)d_ws + 8192);

    lstm_h_kernel<<<BATCH, 128, 0, stream>>>(xi, noise, emb, W_ih, b_ih, b_hh,
                                             hb, rowsum);
    gemm_softmax_kernel<false><<<dim3(NSPLIT, 8), 256, 0, stream>>>(
        hb, fc_w, fc_b, rowsum, out);
    inv_kernel<<<8, 256, 0, stream>>>(rowsum);
    gemm_softmax_kernel<true><<<dim3(NSPLIT, 8), 256, 0, stream>>>(
        hb, fc_w, fc_b, rowsum, out);
}